// Round 11
// baseline (46441.104 us; speedup 1.0000x reference)
//
#include <hip/hip_runtime.h>
#include <hip/hip_bf16.h>
#include <math.h>

#define BATCH   16
#define SEQLEN  2048
#define INDIM   64
#define HIDD    256
#define STATE_D 256
#define MLPD    1024
#define OUTD    128
#define NLAYERS 4
#define M_TOK   (BATCH*SEQLEN)     // 32768 tokens

// ---- scratch in fp32 device globals ----------------------------------------
__device__ float g_h [(size_t)M_TOK*256];   // hidden
__device__ float g_y [(size_t)M_TOK*256];   // LRU output
__device__ float g_bu[(size_t)M_TOK*512];   // Bu / states (re|im); reused as z

// ---------------------------------------------------------------------------
// embed: h[m][n] = sum_k x[m][k] * emb_W[n][k] + emb_b[n]
// ---------------------------------------------------------------------------
__global__ __launch_bounds__(256) void k_emb(
    const float* __restrict__ x, const float* __restrict__ W,
    const float* __restrict__ b)
{
  const int m = blockIdx.x, n = threadIdx.x;
  float acc = 0.f;
  for (int k = 0; k < INDIM; k++)
    acc += x[(size_t)m*INDIM + k] * W[(size_t)n*INDIM + k];
  g_h[(size_t)m*HIDD + n] = acc + b[n];
}

// ---------------------------------------------------------------------------
// Bu[m][s] = (sum_h h[m][h]*(B_re[s][h] + i B_im[s][h])) * exp(ga[s])
// ---------------------------------------------------------------------------
__global__ __launch_bounds__(256) void k_bu(
    const float* __restrict__ Bre, const float* __restrict__ Bim,
    const float* __restrict__ ga)
{
  const int m = blockIdx.x, s = threadIdx.x;
  __shared__ float hr[HIDD];
  hr[s] = g_h[(size_t)m*HIDD + s];
  __syncthreads();
  float sre = 0.f, sim = 0.f;
  for (int k = 0; k < HIDD; k++){
    float hv = hr[k];
    sre += hv * Bre[(size_t)s*HIDD + k];
    sim += hv * Bim[(size_t)s*HIDD + k];
  }
  float g = expf(ga[s]);
  g_bu[(size_t)m*512 + s]       = sre * g;
  g_bu[(size_t)m*512 + 256 + s] = sim * g;
}

// ---------------------------------------------------------------------------
// lam_s = exp(-exp(nu)) * (cos(exp(th)) + i sin(exp(th))); sequential scan.
// ---------------------------------------------------------------------------
__global__ __launch_bounds__(256) void scan_seq(
    const float* __restrict__ nu_log, const float* __restrict__ th_log)
{
  const int b = blockIdx.x, s = threadIdx.x;
  float nu  = expf(nu_log[s]);
  float th  = expf(th_log[s]);
  float mag = expf(-nu);
  float lr  = mag * cosf(th);
  float li  = mag * sinf(th);
  float ar = 0.f, ai = 0.f;
  size_t base = (size_t)b * SEQLEN * 512 + s;
  for (int t = 0; t < SEQLEN; t++){
    size_t o = base + (size_t)t*512;
    float br = g_bu[o];
    float bi = g_bu[o + 256];
    float nr = fmaf(lr, ar, fmaf(-li, ai, br));
    float ni = fmaf(lr, ai, fmaf( li, ar, bi));
    ar = nr; ai = ni;
    g_bu[o]       = ar;
    g_bu[o + 256] = ai;
  }
}

// ---------------------------------------------------------------------------
// y[m][n] = sum_s(re*C_re[n][s] - im*C_im[n][s]) + D[n]*h[m][n]
// ---------------------------------------------------------------------------
__global__ __launch_bounds__(256) void k_y(
    const float* __restrict__ Cre, const float* __restrict__ Cim,
    const float* __restrict__ Dv)
{
  const int m = blockIdx.x, n = threadIdx.x;
  __shared__ float br[512];
  br[n]       = g_bu[(size_t)m*512 + n];
  br[n + 256] = g_bu[(size_t)m*512 + 256 + n];
  __syncthreads();
  float acc = 0.f;
  for (int s = 0; s < STATE_D; s++)
    acc += br[s] * Cre[(size_t)n*STATE_D + s] - br[s + 256] * Cim[(size_t)n*STATE_D + s];
  g_y[(size_t)m*HIDD + n] = acc + Dv[n] * g_h[(size_t)m*HIDD + n];
}

// ---------------------------------------------------------------------------
// z[m][j] = gelu(sum_k y[m][k]*Wh[c*512+j][k] + bh[c*512+j]), 512 threads
// ---------------------------------------------------------------------------
__global__ __launch_bounds__(512) void k_z(
    const float* __restrict__ Wh, const float* __restrict__ bh, int c)
{
  const int m = blockIdx.x, j = threadIdx.x;
  __shared__ float yr[HIDD];
  if (j < HIDD) yr[j] = g_y[(size_t)m*HIDD + j];
  __syncthreads();
  const int row = c*512 + j;
  float acc = 0.f;
  for (int k = 0; k < STATE_D; k++)
    acc += yr[k] * Wh[(size_t)row*STATE_D + k];
  acc += bh[row];
  acc = 0.5f * acc * (1.0f + erff(acc * 0.70710678118654752f));
  g_bu[(size_t)m*512 + j] = acc;
}

// ---------------------------------------------------------------------------
// c==0: h[m][n] = sum_j z[m][j]*Wo[n][j]     + bo[n] + y[m][n]
// c==1: h[m][n] += sum_j z[m][j]*Wo[n][512+j]
// ---------------------------------------------------------------------------
__global__ __launch_bounds__(256) void k_hup(
    const float* __restrict__ Wo, const float* __restrict__ bo, int c)
{
  const int m = blockIdx.x, n = threadIdx.x;
  __shared__ float zr[512];
  zr[n]       = g_bu[(size_t)m*512 + n];
  zr[n + 256] = g_bu[(size_t)m*512 + 256 + n];
  __syncthreads();
  float acc = 0.f;
  for (int j = 0; j < 512; j++)
    acc += zr[j] * Wo[(size_t)n*MLPD + c*512 + j];
  if (c == 0)
    g_h[(size_t)m*HIDD + n] = acc + bo[n] + g_y[(size_t)m*HIDD + n];
  else
    g_h[(size_t)m*HIDD + n] += acc;
}

// ---------------------------------------------------------------------------
// out[m][n] = sum_k h[m][k]*out_W[n][k] + out_b[n]  — FP32 STORE
// (the reference's output dtype is float32; bf16 was the 10-round bug)
// ---------------------------------------------------------------------------
__global__ __launch_bounds__(128) void k_out(
    const float* __restrict__ W, const float* __restrict__ b,
    float* __restrict__ out)
{
  const int m = blockIdx.x, n = threadIdx.x;     // n in [0,128)
  __shared__ float hr[HIDD];
  hr[n]       = g_h[(size_t)m*HIDD + n];
  hr[n + 128] = g_h[(size_t)m*HIDD + 128 + n];
  __syncthreads();
  float acc = 0.f;
  for (int k = 0; k < HIDD; k++)
    acc += hr[k] * W[(size_t)n*HIDD + k];
  out[(size_t)m*OUTD + n] = acc + b[n];
}

// ---------------------------------------------------------------------------
extern "C" void kernel_launch(void* const* d_in, const int* in_sizes, int n_in,
                              void* d_out, int out_size, void* d_ws, size_t ws_size,
                              hipStream_t stream)
{
  (void)d_ws; (void)ws_size; (void)out_size; (void)n_in; (void)in_sizes;
  const float* x      = (const float*)d_in[0];
  const float* emb_W  = (const float*)d_in[1];
  const float* emb_b  = (const float*)d_in[2];
  const float* nu_log = (const float*)d_in[3];
  const float* th_log = (const float*)d_in[4];
  const float* ga_log = (const float*)d_in[5];
  const float* B_re   = (const float*)d_in[6];
  const float* B_im   = (const float*)d_in[7];
  const float* C_re   = (const float*)d_in[8];
  const float* C_im   = (const float*)d_in[9];
  const float* Dv     = (const float*)d_in[10];
  const float* Wh     = (const float*)d_in[11];
  const float* bh     = (const float*)d_in[12];
  const float* Wo     = (const float*)d_in[13];
  const float* bo     = (const float*)d_in[14];
  const float* out_W  = (const float*)d_in[15];
  const float* out_b  = (const float*)d_in[16];
  float* out = (float*)d_out;

  k_emb<<<dim3(M_TOK), dim3(256), 0, stream>>>(x, emb_W, emb_b);

  for (int l = 0; l < NLAYERS; l++){
    k_bu<<<dim3(M_TOK), dim3(256), 0, stream>>>(
        B_re + (size_t)l*STATE_D*HIDD, B_im + (size_t)l*STATE_D*HIDD,
        ga_log + l*STATE_D);

    scan_seq<<<dim3(BATCH), dim3(256), 0, stream>>>(
        nu_log + l*STATE_D, th_log + l*STATE_D);

    k_y<<<dim3(M_TOK), dim3(256), 0, stream>>>(
        C_re + (size_t)l*HIDD*STATE_D, C_im + (size_t)l*HIDD*STATE_D,
        Dv + l*HIDD);

    for (int c = 0; c < 2; c++){
      k_z<<<dim3(M_TOK), dim3(512), 0, stream>>>(
          Wh + (size_t)l*MLPD*STATE_D, bh + l*MLPD, c);
      k_hup<<<dim3(M_TOK), dim3(256), 0, stream>>>(
          Wo + (size_t)l*HIDD*MLPD, bo + l*HIDD, c);
    }
  }

  k_out<<<dim3(M_TOK), dim3(128), 0, stream>>>(out_W, out_b, out);
}

// Round 12
// 3593.907 us; speedup vs baseline: 12.9222x; 12.9222x over previous
//
#include <hip/hip_runtime.h>
#include <hip/hip_bf16.h>
#include <math.h>

#define BATCH   16
#define SEQLEN  2048
#define INDIM   64
#define HIDD    256
#define STATE_D 256
#define MLPD    1024
#define OUTD    128
#define NLAYERS 4
#define M_TOK   (BATCH*SEQLEN)     // 32768 tokens
#define CHUNK   64
#define NCHUNK  (SEQLEN/CHUNK)     // 32 chunks per batch

// ---- scratch in fp32 device globals (proven plumbing, R6–R11) --------------
__device__ float g_h [(size_t)M_TOK*256];
__device__ float g_y [(size_t)M_TOK*256];
__device__ float g_bu[(size_t)M_TOK*512];   // Bu/states (re|im); reused as z
__device__ float g_carry[512*512];
__device__ float g_Bn[512*256];             // packed B_norm (re rows 0-255, im 256-511)
__device__ float g_Cw[256*512];             // packed [Cre | -Cim]

#define SEL_H   0
#define SEL_Y   1
#define SEL_BU  2
#define SEL_BN  3
#define SEL_CW  4
#define SEL_EXT (-1)

__device__ __forceinline__ float* bufsel(int sel){
  switch(sel){
    case SEL_H:  return g_h;
    case SEL_Y:  return g_y;
    case SEL_BU: return g_bu;
    case SEL_BN: return g_Bn;
    default:     return g_Cw;
  }
}

// ---------------------------------------------------------------------------
// Tiled GEMM: C[M,N] = act(A[M,K] @ W[N,K]^T + bias) (+res / +D*res / +=C)
// FLAGS: 1=bias  2=add res  4=add dscale[n]*res  8=accumulate into C
// ACT:   0=none  1=exact GELU
// ---------------------------------------------------------------------------
#define BM 64
#define BN 64
#define BK 16

template<typename TC, int ACT, int FLAGS>
__global__ __launch_bounds__(256) void gemm_k(
    int aSel, const void* aExt, int lda,
    int wSel, const void* wExt, int ldw,
    int cSel, void* cExt, int ldc,
    const float* __restrict__ bias,
    int rSel, int ldres,
    const float* __restrict__ dscale,
    int K)
{
  const float* A = (aSel >= 0) ? bufsel(aSel) : (const float*)aExt;
  const float* W = (wSel >= 0) ? bufsel(wSel) : (const float*)wExt;
  TC*          C = (cSel >= 0) ? (TC*)bufsel(cSel) : (TC*)cExt;
  const float* res = (rSel >= 0) ? bufsel(rSel) : nullptr;

  __shared__ __align__(16) float As[BK][BM+4];
  __shared__ __align__(16) float Ws[BK][BN+4];
  const int tid = threadIdx.x;
  const int tx = tid & 15, ty = tid >> 4;
  const int row0 = blockIdx.y * BM, col0 = blockIdx.x * BN;
  const int lc = tid & 15;   // k offset within tile
  const int lr = tid >> 4;   // row base
  float acc[4][4] = {};
  for (int k0 = 0; k0 < K; k0 += BK){
    #pragma unroll
    for (int i = 0; i < 4; i++){
      As[lc][lr + 16*i] = A[(size_t)(row0 + lr + 16*i)*lda + k0 + lc];
      Ws[lc][lr + 16*i] = W[(size_t)(col0 + lr + 16*i)*ldw + k0 + lc];
    }
    __syncthreads();
    #pragma unroll
    for (int k = 0; k < BK; k++){
      float4 av = *reinterpret_cast<const float4*>(&As[k][ty*4]);
      float4 bv = *reinterpret_cast<const float4*>(&Ws[k][tx*4]);
      float a[4] = {av.x, av.y, av.z, av.w};
      float b[4] = {bv.x, bv.y, bv.z, bv.w};
      #pragma unroll
      for (int i = 0; i < 4; i++)
        #pragma unroll
        for (int j = 0; j < 4; j++)
          acc[i][j] = fmaf(a[i], b[j], acc[i][j]);
    }
    __syncthreads();
  }
  #pragma unroll
  for (int i = 0; i < 4; i++){
    const int r = row0 + ty*4 + i;
    #pragma unroll
    for (int j = 0; j < 4; j++){
      const int cn = col0 + tx*4 + j;
      float v = acc[i][j];
      if (FLAGS & 1) v += bias[cn];
      if (ACT == 1)  v = 0.5f * v * (1.0f + erff(v * 0.70710678118654752f));
      if (FLAGS & 2) v += res[(size_t)r*ldres + cn];
      if (FLAGS & 4) v += dscale[cn] * res[(size_t)r*ldres + cn];
      const size_t o = (size_t)r*ldc + cn;
      if (FLAGS & 8) v += C[o];
      C[o] = v;
    }
  }
}

// ---------------------------------------------------------------------------
// lam_s = exp(-exp(nu)) * (cos(exp(th)) + i sin(exp(th)))
// ---------------------------------------------------------------------------
__device__ __forceinline__ void lam_of(const float* __restrict__ nu_log,
                                       const float* __restrict__ th_log,
                                       int s, float& lr, float& li)
{
  float nu  = expf(nu_log[s]);
  float th  = expf(th_log[s]);
  float mag = expf(-nu);
  lr = mag * cosf(th);
  li = mag * sinf(th);
}

// Local inclusive scan over 64-token chunks (512 blocks); chunk carry out.
// Validated: R4 (this scan) and R5 (sequential) produced bit-identical output.
__global__ __launch_bounds__(256) void scan_local(
    const float* __restrict__ nu_log, const float* __restrict__ th_log)
{
  const int blk = blockIdx.x;          // global chunk id, 0..511
  const int s   = threadIdx.x;
  float lr, li; lam_of(nu_log, th_log, s, lr, li);
  float ar = 0.f, ai = 0.f;
  size_t base = (size_t)blk * CHUNK * 512 + s;
  for (int t = 0; t < CHUNK; t++){
    float br = g_bu[base + (size_t)t*512];
    float bi = g_bu[base + (size_t)t*512 + 256];
    float nr = fmaf(lr, ar, fmaf(-li, ai, br));
    float ni = fmaf(lr, ai, fmaf( li, ar, bi));
    ar = nr; ai = ni;
    g_bu[base + (size_t)t*512]       = ar;
    g_bu[base + (size_t)t*512 + 256] = ai;
  }
  g_carry[(size_t)blk*512 + s]       = ar;
  g_carry[(size_t)blk*512 + 256 + s] = ai;
}

// Fixup: carry-in from preceding chunk carries (lam^64 via 6 squarings),
// then states[t] += lam^{t+1} * carry_in.
__global__ __launch_bounds__(256) void scan_fix(
    const float* __restrict__ nu_log, const float* __restrict__ th_log)
{
  const int blk = blockIdx.x;
  const int c   = blk & (NCHUNK - 1);
  if (c == 0) return;                        // first chunk of each batch
  const int s = threadIdx.x;
  float lr, li; lam_of(nu_log, th_log, s, lr, li);
  float Tr = lr, Ti = li;
  #pragma unroll
  for (int i = 0; i < 6; i++){ float nr = Tr*Tr - Ti*Ti; Ti = 2.f*Tr*Ti; Tr = nr; }
  const int bstart = blk - c;                // first chunk of this batch
  float cr = 0.f, ci = 0.f;
  for (int j = 0; j < c; j++){
    float er = g_carry[(size_t)(bstart + j)*512 + s];
    float ei = g_carry[(size_t)(bstart + j)*512 + 256 + s];
    float nr = fmaf(Tr, cr, fmaf(-Ti, ci, er));
    float ni = fmaf(Tr, ci, fmaf( Ti, cr, ei));
    cr = nr; ci = ni;
  }
  float pr = lr, pi = li;                    // lam^{t+1}
  size_t base = (size_t)blk * CHUNK * 512 + s;
  for (int t = 0; t < CHUNK; t++){
    size_t o = base + (size_t)t*512;
    g_bu[o]       += pr*cr - pi*ci;
    g_bu[o + 256] += pr*ci + pi*cr;
    float nr = pr*lr - pi*li;
    pi = pr*li + pi*lr; pr = nr;
  }
}

// Pack B_norm = (Bre + i*Bim)*exp(ga) into (512 x 256): re rows then im rows
__global__ __launch_bounds__(256) void pack_B(
    const float* __restrict__ Bre, const float* __restrict__ Bim,
    const float* __restrict__ gl)
{
  int idx = blockIdx.x * 256 + threadIdx.x;      // 0..65535
  int s = idx >> 8;
  float g = expf(gl[s]);
  g_Bn[idx]         = Bre[idx] * g;
  g_Bn[65536 + idx] = Bim[idx] * g;
}

// Pack Cw (HID x 512): [Cre | -Cim] so y = bu @ Cw^T = Re(states @ C^T)
__global__ __launch_bounds__(256) void pack_C(
    const float* __restrict__ Cre, const float* __restrict__ Cim)
{
  int idx = blockIdx.x * 256 + threadIdx.x;      // 0..65535
  int h = idx >> 8, s = idx & 255;
  g_Cw[(size_t)h*512 + s]       =  Cre[idx];
  g_Cw[(size_t)h*512 + 256 + s] = -Cim[idx];
}

// ---------------------------------------------------------------------------
extern "C" void kernel_launch(void* const* d_in, const int* in_sizes, int n_in,
                              void* d_out, int out_size, void* d_ws, size_t ws_size,
                              hipStream_t stream)
{
  (void)d_ws; (void)ws_size; (void)out_size; (void)n_in; (void)in_sizes;
  const float* x      = (const float*)d_in[0];
  const float* emb_W  = (const float*)d_in[1];
  const float* emb_b  = (const float*)d_in[2];
  const float* nu_log = (const float*)d_in[3];
  const float* th_log = (const float*)d_in[4];
  const float* ga_log = (const float*)d_in[5];
  const float* B_re   = (const float*)d_in[6];
  const float* B_im   = (const float*)d_in[7];
  const float* C_re   = (const float*)d_in[8];
  const float* C_im   = (const float*)d_in[9];
  const float* Dv     = (const float*)d_in[10];
  const float* Wh     = (const float*)d_in[11];
  const float* bh     = (const float*)d_in[12];
  const float* Wo     = (const float*)d_in[13];
  const float* bo     = (const float*)d_in[14];
  const float* out_W  = (const float*)d_in[15];
  const float* out_b  = (const float*)d_in[16];

  const dim3 blk(256);
  const int MT = M_TOK / BM;               // 512 row tiles

  // embed: h = x @ emb_W^T + emb_b           (32768, 256, 64)
  gemm_k<float, 0, 1><<<dim3(HIDD/BN, MT), blk, 0, stream>>>(
      SEL_EXT, x, INDIM, SEL_EXT, emb_W, INDIM, SEL_H, nullptr, HIDD,
      emb_b, -1, 0, nullptr, INDIM);

  for (int l = 0; l < NLAYERS; l++){
    const float* nu_l = nu_log + l*STATE_D;
    const float* th_l = th_log + l*STATE_D;

    pack_B<<<dim3(256), blk, 0, stream>>>(B_re + (size_t)l*65536,
                                          B_im + (size_t)l*65536,
                                          ga_log + l*STATE_D);
    pack_C<<<dim3(256), blk, 0, stream>>>(C_re + (size_t)l*65536,
                                          C_im + (size_t)l*65536);

    // Bu = h @ Bn^T                          (32768, 512, 256)
    gemm_k<float, 0, 0><<<dim3(512/BN, MT), blk, 0, stream>>>(
        SEL_H, nullptr, HIDD, SEL_BN, nullptr, HIDD, SEL_BU, nullptr, 512,
        nullptr, -1, 0, nullptr, HIDD);

    // chunked parallel scan over L
    scan_local<<<dim3(M_TOK/CHUNK), blk, 0, stream>>>(nu_l, th_l);
    scan_fix  <<<dim3(M_TOK/CHUNK), blk, 0, stream>>>(nu_l, th_l);

    // y = bu @ Cw^T + D*h                    (32768, 256, 512)
    gemm_k<float, 0, 4><<<dim3(HIDD/BN, MT), blk, 0, stream>>>(
        SEL_BU, nullptr, 512, SEL_CW, nullptr, 512, SEL_Y, nullptr, HIDD,
        nullptr, SEL_H, HIDD, Dv + l*HIDD, 512);

    // MLP in two 512-wide chunks; z-chunk lives in g_bu (free after y)
    for (int c = 0; c < 2; c++){
      // z = gelu(y @ Wh_c^T + bh_c)          (32768, 512, 256)
      gemm_k<float, 1, 1><<<dim3(512/BN, MT), blk, 0, stream>>>(
          SEL_Y, nullptr, HIDD,
          SEL_EXT, Wh + (size_t)l*MLPD*STATE_D + (size_t)c*512*STATE_D, STATE_D,
          SEL_BU, nullptr, 512,
          bh + l*MLPD + c*512, -1, 0, nullptr, STATE_D);
      if (c == 0){
        // h = z @ Wo_c^T + bo + y            (32768, 256, 512)
        gemm_k<float, 0, 3><<<dim3(HIDD/BN, MT), blk, 0, stream>>>(
            SEL_BU, nullptr, 512,
            SEL_EXT, Wo + (size_t)l*HIDD*MLPD, MLPD,
            SEL_H, nullptr, HIDD,
            bo + l*HIDD, SEL_Y, HIDD, nullptr, 512);
      } else {
        // h += z @ Wo_c^T
        gemm_k<float, 0, 8><<<dim3(HIDD/BN, MT), blk, 0, stream>>>(
            SEL_BU, nullptr, 512,
            SEL_EXT, Wo + (size_t)l*HIDD*MLPD + 512, MLPD,
            SEL_H, nullptr, HIDD,
            nullptr, -1, 0, nullptr, 512);
      }
    }
  }

  // out = h @ out_W^T + out_b                (32768, 128, 256), fp32 store
  gemm_k<float, 0, 1><<<dim3(OUTD/BN, MT), blk, 0, stream>>>(
      SEL_H, nullptr, HIDD, SEL_EXT, out_W, HIDD, SEL_EXT, d_out, OUTD,
      out_b, -1, 0, nullptr, HIDD);
}

// Round 13
// 1394.826 us; speedup vs baseline: 33.2953x; 2.5766x over previous
//
#include <hip/hip_runtime.h>
#include <hip/hip_bf16.h>
#include <math.h>

typedef __hip_bfloat16 bf16;
typedef __attribute__((ext_vector_type(8))) short bf16x8;   // 8 bf16 = 4 VGPR
typedef __attribute__((ext_vector_type(4))) float f32x4;    // MFMA acc

#define BATCH   16
#define SEQLEN  2048
#define INDIM   64
#define HIDD    256
#define STATE_D 256
#define MLPD    1024
#define OUTD    128
#define NLAYERS 4
#define M_TOK   (BATCH*SEQLEN)     // 32768 tokens
#define CHUNK   64
#define NCHUNK  (SEQLEN/CHUNK)     // 32 chunks per batch

// ---- fp32 masters (residual chain precision) -------------------------------
__device__ float g_h [(size_t)M_TOK*256];
__device__ float g_y [(size_t)M_TOK*256];
__device__ float g_bu[(size_t)M_TOK*512];
__device__ float g_carry[512*512];
// ---- bf16 shadows / packed weights (MFMA operands) -------------------------
__device__ bf16  g_hb [(size_t)M_TOK*256];
__device__ bf16  g_yb [(size_t)M_TOK*256];
__device__ bf16  g_bub[(size_t)M_TOK*512];
__device__ bf16  g_zb [(size_t)M_TOK*1024];
__device__ bf16  g_Bnb[512*256];    // B_norm: rows 0-255 re, 256-511 im
__device__ bf16  g_Cwb[256*512];    // [Cre | -Cim]
__device__ bf16  g_Whb[1024*256];   // layer-local Wh
__device__ bf16  g_Wob[256*1024];   // layer-local Wo

#define SF_H  0
#define SF_Y  1
#define SF_BU 2
#define SB_HB  0
#define SB_YB  1
#define SB_BUB 2
#define SB_ZB  3
#define SB_BNB 4
#define SB_CWB 5
#define SB_WHB 6
#define SB_WOB 7

__device__ __forceinline__ float* buff(int sel){
  switch(sel){ case SF_H: return g_h; case SF_Y: return g_y; default: return g_bu; }
}
__device__ __forceinline__ bf16* bufb(int sel){
  switch(sel){
    case SB_HB:  return g_hb;  case SB_YB:  return g_yb;
    case SB_BUB: return g_bub; case SB_ZB:  return g_zb;
    case SB_BNB: return g_Bnb; case SB_CWB: return g_Cwb;
    case SB_WHB: return g_Whb; default:     return g_Wob; }
}

// ---------------------------------------------------------------------------
// MFMA GEMM: C[M,N] = act(A @ W^T + bias) (+res / +dscale*res)
// A: bf16 [M,K] lda;  W: bf16 [N,K] ldw.  128x128 block, 4 waves, BK=32.
// FLAGS: 1=bias  2=add res  4=add dscale[n]*res.  ACT: 1=exact GELU.
// Writes fp32 out (oFSel>=0) and/or bf16 shadow (oBSel>=0), both ldc.
// LDS row stride 56 bf16 (112B): 16B-aligned b128, 2-way bank alias (free).
// ---------------------------------------------------------------------------
#define LSTR 56

template<int ACT, int FLAGS>
__global__ __launch_bounds__(256) void mfma_gemm(
    int aSel, int lda, int wSel, int ldw,
    int oFSel, int oBSel, int ldc,
    const float* __restrict__ bias,
    int rSel, int ldres,
    const float* __restrict__ dscale,
    int K)
{
  const bf16* A = bufb(aSel);
  const bf16* W = bufb(wSel);
  float* OF = (oFSel >= 0) ? buff(oFSel) : nullptr;
  bf16*  OB = (oBSel >= 0) ? bufb(oBSel) : nullptr;
  const float* res = (rSel >= 0) ? buff(rSel) : nullptr;

  __shared__ __align__(16) unsigned short As[128*LSTR];
  __shared__ __align__(16) unsigned short Ws[128*LSTR];

  const int tid  = threadIdx.x;
  const int row0 = blockIdx.y * 128, col0 = blockIdx.x * 128;
  const int lane = tid & 63;
  const int m16  = lane & 15, quad = lane >> 4;
  const int wv   = tid >> 6;
  const int wm   = (wv & 1) * 64, wn = (wv >> 1) * 64;
  const int sr   = tid >> 2;          // staging row 0..63
  const int sg   = tid & 3;           // staging k-group (8 bf16 each)

  f32x4 acc[4][4] = {};

  for (int k0 = 0; k0 < K; k0 += 32){
    // stage A/W tiles (raw 16B copies; sources are bf16 already)
    *reinterpret_cast<uint4*>(&As[sr*LSTR + sg*8]) =
        *reinterpret_cast<const uint4*>(&A[(size_t)(row0 + sr)*lda + k0 + sg*8]);
    *reinterpret_cast<uint4*>(&As[(sr+64)*LSTR + sg*8]) =
        *reinterpret_cast<const uint4*>(&A[(size_t)(row0 + sr + 64)*lda + k0 + sg*8]);
    *reinterpret_cast<uint4*>(&Ws[sr*LSTR + sg*8]) =
        *reinterpret_cast<const uint4*>(&W[(size_t)(col0 + sr)*ldw + k0 + sg*8]);
    *reinterpret_cast<uint4*>(&Ws[(sr+64)*LSTR + sg*8]) =
        *reinterpret_cast<const uint4*>(&W[(size_t)(col0 + sr + 64)*ldw + k0 + sg*8]);
    __syncthreads();

    bf16x8 af[4], wf[4];
    #pragma unroll
    for (int i = 0; i < 4; i++){
      af[i] = *reinterpret_cast<const bf16x8*>(&As[(wm + 16*i + m16)*LSTR + quad*8]);
      wf[i] = *reinterpret_cast<const bf16x8*>(&Ws[(wn + 16*i + m16)*LSTR + quad*8]);
    }
    #pragma unroll
    for (int i = 0; i < 4; i++)
      #pragma unroll
      for (int j = 0; j < 4; j++)
        acc[i][j] = __builtin_amdgcn_mfma_f32_16x16x32_bf16(af[i], wf[j], acc[i][j], 0, 0, 0);
    __syncthreads();
  }

  // epilogue: C/D layout col=lane&15, row=quad*4+reg  (m89-verified)
  #pragma unroll
  for (int i = 0; i < 4; i++){
    #pragma unroll
    for (int j = 0; j < 4; j++){
      const int col = col0 + wn + 16*j + m16;
      #pragma unroll
      for (int r = 0; r < 4; r++){
        const int row = row0 + wm + 16*i + quad*4 + r;
        float v = acc[i][j][r];
        if (FLAGS & 1) v += bias[col];
        if (ACT == 1)  v = 0.5f * v * (1.0f + erff(v * 0.70710678118654752f));
        if (FLAGS & 2) v += res[(size_t)row*ldres + col];
        if (FLAGS & 4) v += dscale[col] * res[(size_t)row*ldres + col];
        const size_t o = (size_t)row*ldc + col;
        if (OF) OF[o] = v;
        if (OB) OB[o] = __float2bfloat16(v);
      }
    }
  }
}

// ---------------------------------------------------------------------------
// fp32 tiled GEMMs for the small ends (embed, out) — proven R12 structure.
// ---------------------------------------------------------------------------
__global__ __launch_bounds__(256) void emb_gemm(
    const float* __restrict__ x, const float* __restrict__ W,
    const float* __restrict__ b)
{
  __shared__ __align__(16) float Asx[16][68];
  __shared__ __align__(16) float Wsx[16][68];
  const int tid = threadIdx.x;
  const int tx = tid & 15, ty = tid >> 4;
  const int row0 = blockIdx.y * 64, col0 = blockIdx.x * 64;
  const int lc = tid & 15, lr = tid >> 4;
  float acc[4][4] = {};
  for (int k0 = 0; k0 < INDIM; k0 += 16){
    #pragma unroll
    for (int i = 0; i < 4; i++){
      Asx[lc][lr + 16*i] = x[(size_t)(row0 + lr + 16*i)*INDIM + k0 + lc];
      Wsx[lc][lr + 16*i] = W[(size_t)(col0 + lr + 16*i)*INDIM + k0 + lc];
    }
    __syncthreads();
    #pragma unroll
    for (int k = 0; k < 16; k++){
      float4 av = *reinterpret_cast<const float4*>(&Asx[k][ty*4]);
      float4 bv = *reinterpret_cast<const float4*>(&Wsx[k][tx*4]);
      float a[4] = {av.x, av.y, av.z, av.w};
      float b2[4] = {bv.x, bv.y, bv.z, bv.w};
      #pragma unroll
      for (int i = 0; i < 4; i++)
        #pragma unroll
        for (int j = 0; j < 4; j++)
          acc[i][j] = fmaf(a[i], b2[j], acc[i][j]);
    }
    __syncthreads();
  }
  #pragma unroll
  for (int i = 0; i < 4; i++){
    const int r = row0 + ty*4 + i;
    #pragma unroll
    for (int j = 0; j < 4; j++){
      const int cn = col0 + tx*4 + j;
      float v = acc[i][j] + b[cn];
      g_h [(size_t)r*HIDD + cn] = v;
      g_hb[(size_t)r*HIDD + cn] = __float2bfloat16(v);
    }
  }
}

__global__ __launch_bounds__(256) void out_gemm(
    const float* __restrict__ W, const float* __restrict__ b,
    float* __restrict__ out)
{
  __shared__ __align__(16) float Asx[16][68];
  __shared__ __align__(16) float Wsx[16][68];
  const int tid = threadIdx.x;
  const int tx = tid & 15, ty = tid >> 4;
  const int row0 = blockIdx.y * 64, col0 = blockIdx.x * 64;
  const int lc = tid & 15, lr = tid >> 4;
  float acc[4][4] = {};
  for (int k0 = 0; k0 < HIDD; k0 += 16){
    #pragma unroll
    for (int i = 0; i < 4; i++){
      Asx[lc][lr + 16*i] = g_h[(size_t)(row0 + lr + 16*i)*HIDD + k0 + lc];
      Wsx[lc][lr + 16*i] = W[(size_t)(col0 + lr + 16*i)*HIDD + k0 + lc];
    }
    __syncthreads();
    #pragma unroll
    for (int k = 0; k < 16; k++){
      float4 av = *reinterpret_cast<const float4*>(&Asx[k][ty*4]);
      float4 bv = *reinterpret_cast<const float4*>(&Wsx[k][tx*4]);
      float a[4] = {av.x, av.y, av.z, av.w};
      float b2[4] = {bv.x, bv.y, bv.z, bv.w};
      #pragma unroll
      for (int i = 0; i < 4; i++)
        #pragma unroll
        for (int j = 0; j < 4; j++)
          acc[i][j] = fmaf(a[i], b2[j], acc[i][j]);
    }
    __syncthreads();
  }
  #pragma unroll
  for (int i = 0; i < 4; i++){
    const int r = row0 + ty*4 + i;
    #pragma unroll
    for (int j = 0; j < 4; j++){
      const int cn = col0 + tx*4 + j;
      out[(size_t)r*OUTD + cn] = acc[i][j] + b[cn];
    }
  }
}

// ---------------------------------------------------------------------------
// lam_s = exp(-exp(nu)) * (cos(exp(th)) + i sin(exp(th)))
// ---------------------------------------------------------------------------
__device__ __forceinline__ void lam_of(const float* __restrict__ nu_log,
                                       const float* __restrict__ th_log,
                                       int s, float& lr, float& li)
{
  float nu  = expf(nu_log[s]);
  float th  = expf(th_log[s]);
  float mag = expf(-nu);
  lr = mag * cosf(th);
  li = mag * sinf(th);
}

// Local inclusive scan over 64-token chunks (fp32); chunk carry out.
__global__ __launch_bounds__(256) void scan_local(
    const float* __restrict__ nu_log, const float* __restrict__ th_log)
{
  const int blk = blockIdx.x;          // chunk 0..511
  const int s   = threadIdx.x;
  float lr, li; lam_of(nu_log, th_log, s, lr, li);
  float ar = 0.f, ai = 0.f;
  size_t base = (size_t)blk * CHUNK * 512 + s;
  for (int t = 0; t < CHUNK; t++){
    float br = g_bu[base + (size_t)t*512];
    float bi = g_bu[base + (size_t)t*512 + 256];
    float nr = fmaf(lr, ar, fmaf(-li, ai, br));
    float ni = fmaf(lr, ai, fmaf( li, ar, bi));
    ar = nr; ai = ni;
    g_bu[base + (size_t)t*512]       = ar;
    g_bu[base + (size_t)t*512 + 256] = ai;
  }
  g_carry[(size_t)blk*512 + s]       = ar;
  g_carry[(size_t)blk*512 + 256 + s] = ai;
}

// Fixup + bf16 shadow emit (all chunks; correction only for c>0).
__global__ __launch_bounds__(256) void scan_fix(
    const float* __restrict__ nu_log, const float* __restrict__ th_log)
{
  const int blk = blockIdx.x;
  const int c   = blk & (NCHUNK - 1);
  const int s   = threadIdx.x;
  float lr, li; lam_of(nu_log, th_log, s, lr, li);
  float cr = 0.f, ci = 0.f;
  if (c > 0){
    float Tr = lr, Ti = li;
    #pragma unroll
    for (int i = 0; i < 6; i++){ float nr = Tr*Tr - Ti*Ti; Ti = 2.f*Tr*Ti; Tr = nr; }
    const int bstart = blk - c;
    for (int j = 0; j < c; j++){
      float er = g_carry[(size_t)(bstart + j)*512 + s];
      float ei = g_carry[(size_t)(bstart + j)*512 + 256 + s];
      float nr = fmaf(Tr, cr, fmaf(-Ti, ci, er));
      float ni = fmaf(Tr, ci, fmaf( Ti, cr, ei));
      cr = nr; ci = ni;
    }
  }
  float pr = lr, pi = li;                    // lam^{t+1}
  size_t base = (size_t)blk * CHUNK * 512 + s;
  for (int t = 0; t < CHUNK; t++){
    size_t o = base + (size_t)t*512;
    float vr = g_bu[o], vi = g_bu[o + 256];
    if (c > 0){
      vr += pr*cr - pi*ci;
      vi += pr*ci + pi*cr;
      g_bu[o] = vr; g_bu[o + 256] = vi;
      float nr = pr*lr - pi*li;
      pi = pr*li + pi*lr; pr = nr;
    }
    g_bub[o]       = __float2bfloat16(vr);
    g_bub[o + 256] = __float2bfloat16(vi);
  }
}

// Pack B_norm -> bf16 (512 x 256): re rows 0-255, im rows 256-511
__global__ __launch_bounds__(256) void pack_B(
    const float* __restrict__ Bre, const float* __restrict__ Bim,
    const float* __restrict__ gl)
{
  int idx = blockIdx.x * 256 + threadIdx.x;      // 0..65535
  int s = idx >> 8;
  float g = expf(gl[s]);
  g_Bnb[idx]         = __float2bfloat16(Bre[idx] * g);
  g_Bnb[65536 + idx] = __float2bfloat16(Bim[idx] * g);
}

// Pack Cw -> bf16 (256 x 512): [Cre | -Cim]
__global__ __launch_bounds__(256) void pack_C(
    const float* __restrict__ Cre, const float* __restrict__ Cim)
{
  int idx = blockIdx.x * 256 + threadIdx.x;      // 0..65535
  int h = idx >> 8, s = idx & 255;
  g_Cwb[(size_t)h*512 + s]       = __float2bfloat16( Cre[idx]);
  g_Cwb[(size_t)h*512 + 256 + s] = __float2bfloat16(-Cim[idx]);
}

// Straight fp32 -> bf16 weight convert into selected buffer
__global__ __launch_bounds__(256) void conv_bf16(
    const float* __restrict__ src, int dstSel, int n)
{
  int i = blockIdx.x * 256 + threadIdx.x;
  if (i < n) bufb(dstSel)[i] = __float2bfloat16(src[i]);
}

// ---------------------------------------------------------------------------
extern "C" void kernel_launch(void* const* d_in, const int* in_sizes, int n_in,
                              void* d_out, int out_size, void* d_ws, size_t ws_size,
                              hipStream_t stream)
{
  (void)d_ws; (void)ws_size; (void)out_size; (void)n_in; (void)in_sizes;
  const float* x      = (const float*)d_in[0];
  const float* emb_W  = (const float*)d_in[1];
  const float* emb_b  = (const float*)d_in[2];
  const float* nu_log = (const float*)d_in[3];
  const float* th_log = (const float*)d_in[4];
  const float* ga_log = (const float*)d_in[5];
  const float* B_re   = (const float*)d_in[6];
  const float* B_im   = (const float*)d_in[7];
  const float* C_re   = (const float*)d_in[8];
  const float* C_im   = (const float*)d_in[9];
  const float* Dv     = (const float*)d_in[10];
  const float* Wh     = (const float*)d_in[11];
  const float* bh     = (const float*)d_in[12];
  const float* Wo     = (const float*)d_in[13];
  const float* bo     = (const float*)d_in[14];
  const float* out_W  = (const float*)d_in[15];
  const float* out_b  = (const float*)d_in[16];

  const dim3 blk(256);

  // embed: h = x @ emb_W^T + emb_b  (fp32 GEMM + bf16 shadow)
  emb_gemm<<<dim3(HIDD/64, M_TOK/64), blk, 0, stream>>>(x, emb_W, emb_b);

  for (int l = 0; l < NLAYERS; l++){
    pack_B<<<dim3(256), blk, 0, stream>>>(B_re + (size_t)l*65536,
                                          B_im + (size_t)l*65536,
                                          ga_log + l*STATE_D);
    pack_C<<<dim3(256), blk, 0, stream>>>(C_re + (size_t)l*65536,
                                          C_im + (size_t)l*65536);
    conv_bf16<<<dim3(1024), blk, 0, stream>>>(Wh + (size_t)l*262144, SB_WHB, 262144);
    conv_bf16<<<dim3(1024), blk, 0, stream>>>(Wo + (size_t)l*262144, SB_WOB, 262144);

    // Bu = h @ Bn^T   (32768 x 512 x 256) -> g_bu fp32
    mfma_gemm<0, 0><<<dim3(4, M_TOK/128), blk, 0, stream>>>(
        SB_HB, HIDD, SB_BNB, HIDD, SF_BU, -1, 512,
        nullptr, -1, 0, nullptr, HIDD);

    // chunked scan (fp32) + bf16 shadow
    scan_local<<<dim3(M_TOK/CHUNK), blk, 0, stream>>>(nu_log + l*STATE_D, th_log + l*STATE_D);
    scan_fix  <<<dim3(M_TOK/CHUNK), blk, 0, stream>>>(nu_log + l*STATE_D, th_log + l*STATE_D);

    // y = states @ Cw^T + D*h   (32768 x 256 x 512) -> g_y + g_yb
    mfma_gemm<0, 4><<<dim3(2, M_TOK/128), blk, 0, stream>>>(
        SB_BUB, 512, SB_CWB, 512, SF_Y, SB_YB, HIDD,
        nullptr, SF_H, HIDD, Dv + l*HIDD, 512);

    // z = gelu(y @ Wh^T + bh)   (32768 x 1024 x 256) -> g_zb only
    mfma_gemm<1, 1><<<dim3(8, M_TOK/128), blk, 0, stream>>>(
        SB_YB, HIDD, SB_WHB, STATE_D, -1, SB_ZB, MLPD,
        bh + l*MLPD, -1, 0, nullptr, STATE_D);

    // h = z @ Wo^T + bo + y     (32768 x 256 x 1024) -> g_h + g_hb
    mfma_gemm<0, 3><<<dim3(2, M_TOK/128), blk, 0, stream>>>(
        SB_ZB, MLPD, SB_WOB, MLPD, SF_H, SB_HB, HIDD,
        bo + l*HIDD, SF_Y, HIDD, nullptr, MLPD);
  }

  // out = h @ out_W^T + out_b  (fp32 GEMM, fp32 store)
  out_gemm<<<dim3(OUTD/64, M_TOK/64), blk, 0, stream>>>(out_W, out_b, (float*)d_out);
}